// Round 5
// baseline (356.898 us; speedup 1.0000x reference)
//
#include <hip/hip_runtime.h>
#include <stdint.h>

// x [B=32, C=512, H=32, W=32] fp32, 32 groups, S = H*W = 1024. All I/O fp32.
// Internal tensors bf16: xt[b][s][c], qkt[b][s][1024] (q|k fused), v[b][d][s],
// Sc/P[b][s][t] bf16, o_t[b][s][c]. All GEMMs NT (Out[m][n] = sum_k A[m][k]B[n][k])
// on mfma_f32_16x16x32_bf16:
//   A-frag: A[m=lane&15][k=quad*8+j]  B-frag: B[n=lane&15][k=quad*8+j]
//   C/D:    col=lane&15, row=quad*4+reg
// R7: bijective XCD-aware block swizzle (T1): scores FETCH 166->49MB.
// R10: fine-phase 256x256/BK=64 8-wave kernel for ALL GEMMs (47us, MfmaUtil 28%).
// R11: counted vmcnt (T4, the m201 rule). R10 post-mortem: vmcnt(0) at tile
//   start waits on staging loads issued only ~1 phase earlier -> every tile
//   pays the tail-load latency, all 8 waves gated on the slowest (barrier).
//   Now: k-major phases (ph0 m0-3 x k0, ph1 m4-7 x k0, ph2 m0-3 x k1,
//   ph3 m4-7 x k1); staging ph0-1 covers khalf0 of t+1, ph2-3 covers khalf1;
//   waits: vmcnt(4) at tile start (drains khalf0, issued a full tile ago) and
//   vmcnt(4) before ph2 (drains khalf1) -- never 0 in the steady-state loop.
#define Bsz 32
#define Cch 512
#define Ssp 1024
#define Grp 32
#define CPG 16

typedef unsigned short u16;
typedef __attribute__((ext_vector_type(8))) short bf16x8;
typedef __attribute__((ext_vector_type(4))) float f32x4;

__device__ __forceinline__ float bf2f(u16 u) {
  union { float f; uint32_t i; } w; w.i = ((uint32_t)u) << 16; return w.f;
}
__device__ __forceinline__ u16 f2bf(float f) {
  union { float f; uint32_t i; } w; w.f = f;
  uint32_t r = w.i + 0x7fffu + ((w.i >> 16) & 1u);  // RNE
  return (u16)(r >> 16);
}

__device__ __forceinline__ void gload_lds16(const u16* g, u16* l) {
  __builtin_amdgcn_global_load_lds(
      (const __attribute__((address_space(1))) uint32_t*)g,
      (__attribute__((address_space(3))) uint32_t*)l, 16, 0, 0);
}

// ---------------- GN stats: one block per (b,g) -> per-channel affine (A,B) ----
__global__ __launch_bounds__(256) void gnstats_kernel(
    const float* __restrict__ x, const float* __restrict__ scale,
    const float* __restrict__ bias, float2* __restrict__ stats) {
  int b = blockIdx.x >> 5;
  int g = blockIdx.x & 31;
  size_t base = ((size_t)b * Cch + (size_t)g * CPG) * Ssp;
  const float4* xv = (const float4*)(x + base);

  float sum = 0.f, sumsq = 0.f;
#pragma unroll
  for (int it = 0; it < 16; ++it) {
    float4 v = xv[threadIdx.x + 256 * it];
    sum += (v.x + v.y) + (v.z + v.w);
    sumsq += (v.x * v.x + v.y * v.y) + (v.z * v.z + v.w * v.w);
  }
#pragma unroll
  for (int off = 32; off > 0; off >>= 1) {
    sum += __shfl_xor(sum, off);
    sumsq += __shfl_xor(sumsq, off);
  }
  __shared__ float sm[8];
  int wid = threadIdx.x >> 6;
  if ((threadIdx.x & 63) == 0) { sm[wid] = sum; sm[4 + wid] = sumsq; }
  __syncthreads();
  sum = sm[0] + sm[1] + sm[2] + sm[3];
  sumsq = sm[4] + sm[5] + sm[6] + sm[7];
  float mean = sum * (1.f / 16384.f);
  float var = sumsq * (1.f / 16384.f) - mean * mean;
  float rstd = rsqrtf(var + 1e-6f);
  if (threadIdx.x < CPG) {
    int c = g * CPG + threadIdx.x;
    float sc = scale[c] * rstd;
    stats[(size_t)b * Cch + c] = make_float2(sc, bias[c] - mean * sc);
  }
}

// ---------------- x[b][c][s] fp32 -> xt[b][s][c] bf16 with GN affine ----------
__global__ __launch_bounds__(256) void xpose_gn(
    const float* __restrict__ x, const float2* __restrict__ stats,
    u16* __restrict__ xt) {
  __shared__ float T[64][65];
  int b = blockIdx.z;
  int s0 = blockIdx.x * 64, c0 = blockIdx.y * 64;
  int t = threadIdx.x;
  {
    int tx = t & 15, ty = t >> 4;
    const float* xb = x + ((size_t)b * Cch + c0) * Ssp + s0;
#pragma unroll
    for (int i = 0; i < 4; ++i) {
      int c = ty + 16 * i;
      float2 af = stats[(size_t)b * Cch + c0 + c];
      float4 v = *(const float4*)&xb[(size_t)c * Ssp + tx * 4];
      T[c][tx * 4 + 0] = v.x * af.x + af.y;
      T[c][tx * 4 + 1] = v.y * af.x + af.y;
      T[c][tx * 4 + 2] = v.z * af.x + af.y;
      T[c][tx * 4 + 3] = v.w * af.x + af.y;
    }
  }
  __syncthreads();
  {
    int cx = t & 7, sy = t >> 3;
    u16* ob = xt + ((size_t)b * Ssp + s0) * Cch + c0;
#pragma unroll
    for (int i = 0; i < 2; ++i) {
      int s = sy + 32 * i;
      union { u16 h[8]; uint4 v4; } pk;
#pragma unroll
      for (int j = 0; j < 8; ++j) pk.h[j] = f2bf(T[cx * 8 + j][s]);
      *(uint4*)&ob[(size_t)s * Cch + cx * 8] = pk.v4;
    }
  }
}

// ---------------- W[c][d] fp32 (512x512) -> Wt[d][c] bf16, 4 weights ----------
__global__ __launch_bounds__(256) void wxpose(
    const float* __restrict__ w0, const float* __restrict__ w1,
    const float* __restrict__ w2, const float* __restrict__ w3,
    u16* __restrict__ dst) {
  const float* W = blockIdx.z == 0 ? w0 : blockIdx.z == 1 ? w1
                   : blockIdx.z == 2 ? w2 : w3;
  u16* D = dst + (size_t)blockIdx.z * Cch * Cch;
  __shared__ float T[64][65];
  int d0 = blockIdx.x * 64, c0 = blockIdx.y * 64;
  int t = threadIdx.x;
  {
    int tx = t & 15, ty = t >> 4;
#pragma unroll
    for (int i = 0; i < 4; ++i) {
      int c = ty + 16 * i;
      float4 v = *(const float4*)&W[(size_t)(c0 + c) * Cch + d0 + tx * 4];
      T[c][tx * 4 + 0] = v.x; T[c][tx * 4 + 1] = v.y;
      T[c][tx * 4 + 2] = v.z; T[c][tx * 4 + 3] = v.w;
    }
  }
  __syncthreads();
  {
    int cx = t & 7, dy = t >> 3;
#pragma unroll
    for (int i = 0; i < 2; ++i) {
      int d = dy + 32 * i;
      union { u16 h[8]; uint4 v4; } pk;
#pragma unroll
      for (int j = 0; j < 8; ++j) pk.h[j] = f2bf(T[cx * 8 + j][d]);
      *(uint4*)&D[(size_t)(d0 + d) * Cch + c0 + cx * 8] = pk.v4;
    }
  }
}

// -------- R11: 256x256 BK=64 8-wave fine-phase NT GEMM, counted vmcnt ---------
// 8 waves 2(M)x4(N); per-wave 128x64 = 8 m-frags x 4 n-frags (32 f32x4 acc).
// LDS per operand: 2 bufs x 32KB; buf = [khalf][16 segs][16rows x 32k unit],
// unit = proven row-pair-XOR layout (pair-line q=r>>1; logical chunk
// c=(r&1)*4+k/8; phys p = c^(q&7); 2-way max bank aliasing = free).
// Staging: unit (su = (p&1)*8+wave, kh = p>>1) of tile t+1 staged at phase p of
// tile t -> ph0-1 stage khalf0, ph2-3 stage khalf1 (2 gload_lds/wave/phase).
// Waits: vmcnt(4) at tile start (drains t's khalf0: issued >= a full tile ago,
// latency covered; khalf1's 4 still in flight) and vmcnt(4) before ph2 (drains
// khalf1; 4 newest = t+1 khalf0 staging stay in flight). Never 0 in-loop.
// EPI 0: bf16 + bias(n<512?bias:b2)  EPI 1: bf16 + bias[m]  EPI 2: bf16 *scale
// EPI 3: bf16                        EPI 4: f32 + bias[m] + resid
template <int EPI>
__global__ __launch_bounds__(512, 2) void mfma_ntf(
    const u16* __restrict__ A, size_t sAb, int lda,
    const u16* __restrict__ B, size_t sBb, int ldb,
    void* __restrict__ Out, size_t sOb, int ldo,
    const float* __restrict__ bias,
    const float* __restrict__ bias2_or_resid, size_t sRb, int K) {
  __shared__ u16 As[2 * 16384];  // 64 KB
  __shared__ u16 Bs[2 * 16384];  // 64 KB

  // bijective XCD-aware swizzle (R7)
  const int nx = gridDim.x, ny = gridDim.y;
  const int pb = nx * ny;
  const int nwg = pb * gridDim.z;
  const int flat = (blockIdx.z * ny + blockIdx.y) * nx + blockIdx.x;
  const int qq = nwg >> 3, rr = nwg & 7;
  const int xcd = flat & 7, lid = flat >> 3;
  const int nf2 = (xcd < rr ? xcd * (qq + 1) : rr * (qq + 1) + (xcd - rr) * qq) + lid;
  const int b = nf2 / pb;
  const int rem = nf2 - b * pb;
  const int m0 = (rem / nx) * 256, n0 = (rem % nx) * 256;

  const int tid = threadIdx.x;
  const int lane = tid & 63, wave = tid >> 6;  // 0..7
  const int wm = wave >> 2, wn = wave & 3;     // 2(M) x 4(N)
  const int quad = lane >> 4, l16 = lane & 15;

  // staging decode (proven): phys chunk p = lane&7 of pair q' = lane>>3 within
  // a 16-row unit; logical c = p ^ q' -> row 2q' + (c>>2), k-off (c&3)*8.
  const int sp = lane & 7, sq = lane >> 3;
  const int scl = sp ^ sq;
  const int srow = 2 * sq + (scl >> 2);
  const int scol = (scl & 3) * 8;

  // fragment-read per-lane offset within a 512-elem unit
  const int vbase =
      ((l16 >> 1) << 6) + ((((l16 & 1) << 2) | quad) ^ (l16 >> 1)) * 8;

  const u16* Ab = A + (size_t)b * sAb + (size_t)m0 * lda;
  const u16* Bb = B + (size_t)b * sBb + (size_t)n0 * ldb;

  f32x4 acc[8][4] = {};

  // stage unit (su=(p&1)*8+wave, kh=p>>1) of tile (kt1) into buffer nbuf
#define STG(p, kt1, nbuf)                                                      \
  {                                                                            \
    const int su_ = ((p) & 1) * 8 + wave;                                      \
    const int kh_ = (p) >> 1;                                                  \
    gload_lds16(Ab + (size_t)(su_ * 16 + srow) * lda + (kt1) * 64 + kh_ * 32 + \
                    scol,                                                      \
                As + (nbuf) * 16384 + kh_ * 8192 + su_ * 512);                 \
    gload_lds16(Bb + (size_t)(su_ * 16 + srow) * ldb + (kt1) * 64 + kh_ * 32 + \
                    scol,                                                      \
                Bs + (nbuf) * 16384 + kh_ * 8192 + su_ * 512);                 \
  }

  // fragment loads from buf cur
#define LDA(mf, kk) \
  (*(const bf16x8*)&As[cur * 16384 + (kk) * 8192 + (wm * 8 + (mf)) * 512 + vbase])
#define LDB(nf, kk) \
  (*(const bf16x8*)&Bs[cur * 16384 + (kk) * 8192 + (wn * 4 + (nf)) * 512 + vbase])

#define BAR asm volatile("s_barrier" ::: "memory")
#define WAIT_VM(n) asm volatile("s_waitcnt vmcnt(" #n ")" ::: "memory")
#define WAIT_LGKM0                                    \
  asm volatile("s_waitcnt lgkmcnt(0)" ::: "memory");  \
  __builtin_amdgcn_sched_barrier(0)

  // prologue: stage tile 0 into buf 0 (8 loads/wave)
#pragma unroll
  for (int p = 0; p < 4; ++p) STG(p, 0, 0)

  const int nk = K >> 6;
  bf16x8 bf[4], a[4];
  for (int kt = 0; kt < nk; ++kt) {
    const int cur = kt & 1;
    const int nbuf = cur ^ 1;
    const bool nxt = (kt + 1 < nk);
    // ---- ph0: khalf0 ready; B k0 + A m0-3 k0 -> mfma m0-3 x k0
    WAIT_VM(4);  // drains t's khalf0 (oldest 4); khalf1's 4 still in flight
    BAR;         // all waves' khalf0 loads complete -> buf cur kh0 valid
#pragma unroll
    for (int i = 0; i < 4; ++i) bf[i] = LDB(i, 0);
#pragma unroll
    for (int i = 0; i < 4; ++i) a[i] = LDA(i, 0);
    if (nxt) STG(0, kt + 1, nbuf)
    BAR;
    WAIT_LGKM0;
    __builtin_amdgcn_s_setprio(1);
#pragma unroll
    for (int mf = 0; mf < 4; ++mf)
#pragma unroll
      for (int nf = 0; nf < 4; ++nf)
        acc[mf][nf] = __builtin_amdgcn_mfma_f32_16x16x32_bf16(
            a[mf], bf[nf], acc[mf][nf], 0, 0, 0);
    __builtin_amdgcn_s_setprio(0);
    // ---- ph1: A m4-7 k0 (B k0 live) -> mfma m4-7 x k0
#pragma unroll
    for (int i = 0; i < 4; ++i) a[i] = LDA(4 + i, 0);
    if (nxt) STG(1, kt + 1, nbuf)
    BAR;
    WAIT_LGKM0;
    __builtin_amdgcn_s_setprio(1);
#pragma unroll
    for (int mf = 0; mf < 4; ++mf)
#pragma unroll
      for (int nf = 0; nf < 4; ++nf)
        acc[4 + mf][nf] = __builtin_amdgcn_mfma_f32_16x16x32_bf16(
            a[mf], bf[nf], acc[4 + mf][nf], 0, 0, 0);
    __builtin_amdgcn_s_setprio(0);
    // ---- ph2: khalf1 ready; B k1 + A m0-3 k1 -> mfma m0-3 x k1
    if (nxt) { WAIT_VM(4); } else { WAIT_VM(0); }
    BAR;  // all waves' khalf1 loads complete -> buf cur kh1 valid
#pragma unroll
    for (int i = 0; i < 4; ++i) bf[i] = LDB(i, 1);
#pragma unroll
    for (int i = 0; i < 4; ++i) a[i] = LDA(i, 1);
    if (nxt) STG(2, kt + 1, nbuf)
    BAR;
    WAIT_LGKM0;
    __builtin_amdgcn_s_setprio(1);
#pragma unroll
    for (int mf = 0; mf < 4; ++mf)
#pragma unroll
      for (int nf = 0; nf < 4; ++nf)
        acc[mf][nf] = __builtin_amdgcn_mfma_f32_16x16x32_bf16(
            a[mf], bf[nf], acc[mf][nf], 0, 0, 0);
    __builtin_amdgcn_s_setprio(0);
    // ---- ph3: A m4-7 k1 (B k1 live) -> mfma m4-7 x k1
#pragma unroll
    for (int i = 0; i < 4; ++i) a[i] = LDA(4 + i, 1);
    if (nxt) STG(3, kt + 1, nbuf)
    BAR;
    WAIT_LGKM0;
    __builtin_amdgcn_s_setprio(1);
#pragma unroll
    for (int mf = 0; mf < 4; ++mf)
#pragma unroll
      for (int nf = 0; nf < 4; ++nf)
        acc[4 + mf][nf] = __builtin_amdgcn_mfma_f32_16x16x32_bf16(
            a[mf], bf[nf], acc[4 + mf][nf], 0, 0, 0);
    __builtin_amdgcn_s_setprio(0);
  }
#undef STG
#undef LDA
#undef LDB

  const float SCALE = 0.044194173824159216f;  // 512^-0.5
#pragma unroll
  for (int mf = 0; mf < 8; ++mf) {
#pragma unroll
    for (int nf = 0; nf < 4; ++nf) {
      int n = n0 + wn * 64 + nf * 16 + l16;
      float bn = 0.f;
      if constexpr (EPI == 0)
        bn = (n < 512) ? bias[n] : bias2_or_resid[n - 512];
#pragma unroll
      for (int reg = 0; reg < 4; ++reg) {
        int m = m0 + wm * 128 + mf * 16 + quad * 4 + reg;
        float v = acc[mf][nf][reg];
        size_t idx = (size_t)b * sOb + (size_t)m * ldo + n;
        if constexpr (EPI == 0) {
          ((u16*)Out)[idx] = f2bf(v + bn);
        } else if constexpr (EPI == 1) {
          ((u16*)Out)[idx] = f2bf(v + bias[m]);
        } else if constexpr (EPI == 2) {
          ((u16*)Out)[idx] = f2bf(v * SCALE);
        } else if constexpr (EPI == 3) {
          ((u16*)Out)[idx] = f2bf(v);
        } else {
          ((float*)Out)[idx] =
              v + bias[m] + bias2_or_resid[(size_t)b * sRb + (size_t)m * ldo + n];
        }
      }
    }
  }
}

// ---------------- Softmax over bf16 rows of Sc [nb*S][S], in place ------------
__global__ __launch_bounds__(256) void softmax_kernel(u16* __restrict__ Sc) {
  size_t row = blockIdx.x;
  u16* rp = Sc + row * (size_t)Ssp;
  uint2 u = ((const uint2*)rp)[threadIdx.x];  // 4 bf16
  const u16* ph = (const u16*)&u;
  float v0 = bf2f(ph[0]), v1 = bf2f(ph[1]), v2 = bf2f(ph[2]), v3 = bf2f(ph[3]);
  float mx = fmaxf(fmaxf(v0, v1), fmaxf(v2, v3));
#pragma unroll
  for (int off = 32; off > 0; off >>= 1) mx = fmaxf(mx, __shfl_xor(mx, off));
  __shared__ float sm[4];
  __shared__ float sd[4];
  int wid = threadIdx.x >> 6;
  if ((threadIdx.x & 63) == 0) sm[wid] = mx;
  __syncthreads();  // also: all row reads complete before any write below
  mx = fmaxf(fmaxf(sm[0], sm[1]), fmaxf(sm[2], sm[3]));
  float e0 = __expf(v0 - mx), e1 = __expf(v1 - mx);
  float e2 = __expf(v2 - mx), e3 = __expf(v3 - mx);
  float s = e0 + e1 + e2 + e3;
#pragma unroll
  for (int off = 32; off > 0; off >>= 1) s += __shfl_xor(s, off);
  if ((threadIdx.x & 63) == 0) sd[wid] = s;
  __syncthreads();
  s = sd[0] + sd[1] + sd[2] + sd[3];
  float inv = 1.f / s;
  union { u16 s4[4]; uint2 v2; } pk;
  pk.s4[0] = f2bf(e0 * inv); pk.s4[1] = f2bf(e1 * inv);
  pk.s4[2] = f2bf(e2 * inv); pk.s4[3] = f2bf(e3 * inv);
  ((uint2*)rp)[threadIdx.x] = pk.v2;
}

extern "C" void kernel_launch(void* const* d_in, const int* in_sizes, int n_in,
                              void* d_out, int out_size, void* d_ws, size_t ws_size,
                              hipStream_t stream) {
  (void)in_sizes; (void)n_in; (void)out_size;
  const float* x   = (const float*)d_in[0];
  const float* gns = (const float*)d_in[1];
  const float* gnb = (const float*)d_in[2];
  const float* Wq  = (const float*)d_in[3];
  const float* bq  = (const float*)d_in[4];
  const float* Wk  = (const float*)d_in[5];
  const float* bk  = (const float*)d_in[6];
  const float* Wv  = (const float*)d_in[7];
  const float* bv  = (const float*)d_in[8];
  const float* Wt  = (const float*)d_in[9];
  const float* bt  = (const float*)d_in[10];
  float* out = (float*)d_out;
  char* ws = (char*)d_ws;

  // Workspace:
  //   qkt @ 0MB   (64MB bf16 [b][s][1024], q|k fused) -> o_t aliases its start
  //   v   @ 64MB  (32MB bf16 [b][d][s])
  //   W_t @ 96MB  (4 x 0.5MB bf16 [d][c]: q,k,v,t -> Wq|Wk contiguous = fused N)
  //   stats @98MB (256KB float2)
  //   xt  @ 99MB  (32MB bf16 [b][s][c]) -> dead after projections
  //   Sc  @ 99MB  (NB*2MB bf16, overlays xt; softmax in place)
  const size_t QKSZ = (size_t)Bsz * Ssp * 1024 * 2;  // 64 MB
  u16* qkt = (u16*)ws;
  u16* vv  = (u16*)(ws + QKSZ);
  u16* Wts = (u16*)(ws + (96ull << 20));
  float2* stats = (float2*)(ws + (98ull << 20));
  u16* xt  = (u16*)(ws + (99ull << 20));
  u16* Sc  = xt;
  u16* ot  = qkt;

  int NB;  // batches per score chunk (Sc = NB*2MB @ 99MB); ws_size is constant
  if (ws_size >= (163ull << 20)) NB = 32;
  else if (ws_size >= (131ull << 20)) NB = 16;
  else NB = 8;

  const size_t WSZ = (size_t)Cch * Cch;
  u16* Wvt = Wts + 2 * WSZ;
  u16* Wtt = Wts + 3 * WSZ;

  const size_t sSC  = (size_t)Ssp * Cch;   // xt / o_t per-batch elems
  const size_t sQK  = (size_t)Ssp * 1024;  // qkt per-batch elems
  const size_t sCS  = (size_t)Cch * Ssp;   // v / x / out per-batch elems
  const size_t sScB = (size_t)Ssp * Ssp;   // score per-batch elems (bf16)
  dim3 blk(256);
  dim3 blk8(512);

  gnstats_kernel<<<dim3(Bsz * Grp), blk, 0, stream>>>(x, gns, gnb, stats);
  xpose_gn<<<dim3(Ssp / 64, Cch / 64, Bsz), blk, 0, stream>>>(x, stats, xt);
  wxpose<<<dim3(8, 8, 4), blk, 0, stream>>>(Wq, Wk, Wv, Wt, Wts);

  // Grids: x = N/256, y = M/256, z = batch
  // fused q|k: m=s(1024), n=dq|dk(1024), k=c(512): A=xt, B=Wq_t|Wk_t
  mfma_ntf<0><<<dim3(4, 4, Bsz), blk8, 0, stream>>>(
      xt, sSC, Cch, Wts, 0, Cch, qkt, sQK, 1024, bq, bk, 0, Cch);
  // v: m=d(512), n=s(1024), k=c(512): A=Wv_t, B=xt -> v[d][s] + bias[m]
  mfma_ntf<1><<<dim3(4, 2, Bsz), blk8, 0, stream>>>(
      Wvt, 0, Cch, xt, sSC, Cch, vv, sCS, Ssp, bv, nullptr, 0, Cch);

  for (int b0 = 0; b0 < Bsz; b0 += NB) {
    int nb = (b0 + NB <= Bsz) ? NB : (Bsz - b0);
    // scores: m=s, n=s', k=d: A=q (qkt+0), B=k (qkt+512) -> Sc bf16 * C^-0.5
    mfma_ntf<2><<<dim3(4, 4, nb), blk8, 0, stream>>>(
        qkt + b0 * sQK, sQK, 1024, qkt + b0 * sQK + 512, sQK, 1024,
        Sc, sScB, Ssp, nullptr, nullptr, 0, Cch);
    softmax_kernel<<<dim3(nb * Ssp), blk, 0, stream>>>(Sc);
    // PV: m=s(1024), n=c(512), k=t(1024): A=P bf16, B=v -> o_t[s][c]
    mfma_ntf<3><<<dim3(2, 4, nb), blk8, 0, stream>>>(
        Sc, sScB, Ssp, vv + b0 * sCS, sCS, Ssp,
        ot + b0 * sSC, sSC, Cch, nullptr, nullptr, 0, Ssp);
  }

  // final: m=d(512), n=s(1024), k=c(512): A=Wt_t, B=o_t -> fp32 +bias[m]+x
  mfma_ntf<4><<<dim3(4, 2, Bsz), blk8, 0, stream>>>(
      Wtt, 0, Cch, ot, sSC, Cch, out, sCS, Ssp, bt, x, sCS, Cch);
}

// Round 6
// 345.359 us; speedup vs baseline: 1.0334x; 1.0334x over previous
//
#include <hip/hip_runtime.h>
#include <stdint.h>

// x [B=32, C=512, H=32, W=32] fp32, 32 groups, S = H*W = 1024. All I/O fp32.
// Internal tensors bf16: xt[b][s][c], qkt[b][s][1024] (q|k fused), v[b][d][s],
// Sc/P[b][s][t] bf16, o_t[b][s][c]. All GEMMs NT (Out[m][n] = sum_k A[m][k]B[n][k])
// on mfma_f32_16x16x32_bf16:
//   A-frag: A[m=lane&15][k=quad*8+j]  B-frag: B[n=lane&15][k=quad*8+j]
//   C/D:    col=lane&15, row=quad*4+reg
// R7: bijective XCD-aware block swizzle (T1): scores FETCH 166->49MB.
// R10/R11: fine-phase 256x256/BK=64 8-wave kernel, counted vmcnt -> NULL.
// R12: serialized-pipes fix. Cycle audit: per CU per K-tile MFMA=2480cy,
//   ds_read pipe=2300cy, and the 8-barrier lockstep structure ALTERNATED them
//   (reads before barrier, MFMA after) -> 7.3k cy/tile measured = serial sum.
//   Now per khalf: issue ALL 12 ds_reads, lgkmcnt(4) -> MFMA m0-3 runs while
//   A m4-7's reads drain on the LDS pipe, lgkmcnt(0) -> MFMA m4-7. Barriers
//   cut 8->2 per tile (only at the two khalf-validity points, each right after
//   its counted vm-wait). Staging/layout/decode identical to R11 (proven).
#define Bsz 32
#define Cch 512
#define Ssp 1024
#define Grp 32
#define CPG 16

typedef unsigned short u16;
typedef __attribute__((ext_vector_type(8))) short bf16x8;
typedef __attribute__((ext_vector_type(4))) float f32x4;

__device__ __forceinline__ float bf2f(u16 u) {
  union { float f; uint32_t i; } w; w.i = ((uint32_t)u) << 16; return w.f;
}
__device__ __forceinline__ u16 f2bf(float f) {
  union { float f; uint32_t i; } w; w.f = f;
  uint32_t r = w.i + 0x7fffu + ((w.i >> 16) & 1u);  // RNE
  return (u16)(r >> 16);
}

__device__ __forceinline__ void gload_lds16(const u16* g, u16* l) {
  __builtin_amdgcn_global_load_lds(
      (const __attribute__((address_space(1))) uint32_t*)g,
      (__attribute__((address_space(3))) uint32_t*)l, 16, 0, 0);
}

// ---------------- GN stats: one block per (b,g) -> per-channel affine (A,B) ----
__global__ __launch_bounds__(256) void gnstats_kernel(
    const float* __restrict__ x, const float* __restrict__ scale,
    const float* __restrict__ bias, float2* __restrict__ stats) {
  int b = blockIdx.x >> 5;
  int g = blockIdx.x & 31;
  size_t base = ((size_t)b * Cch + (size_t)g * CPG) * Ssp;
  const float4* xv = (const float4*)(x + base);

  float sum = 0.f, sumsq = 0.f;
#pragma unroll
  for (int it = 0; it < 16; ++it) {
    float4 v = xv[threadIdx.x + 256 * it];
    sum += (v.x + v.y) + (v.z + v.w);
    sumsq += (v.x * v.x + v.y * v.y) + (v.z * v.z + v.w * v.w);
  }
#pragma unroll
  for (int off = 32; off > 0; off >>= 1) {
    sum += __shfl_xor(sum, off);
    sumsq += __shfl_xor(sumsq, off);
  }
  __shared__ float sm[8];
  int wid = threadIdx.x >> 6;
  if ((threadIdx.x & 63) == 0) { sm[wid] = sum; sm[4 + wid] = sumsq; }
  __syncthreads();
  sum = sm[0] + sm[1] + sm[2] + sm[3];
  sumsq = sm[4] + sm[5] + sm[6] + sm[7];
  float mean = sum * (1.f / 16384.f);
  float var = sumsq * (1.f / 16384.f) - mean * mean;
  float rstd = rsqrtf(var + 1e-6f);
  if (threadIdx.x < CPG) {
    int c = g * CPG + threadIdx.x;
    float sc = scale[c] * rstd;
    stats[(size_t)b * Cch + c] = make_float2(sc, bias[c] - mean * sc);
  }
}

// ---------------- x[b][c][s] fp32 -> xt[b][s][c] bf16 with GN affine ----------
__global__ __launch_bounds__(256) void xpose_gn(
    const float* __restrict__ x, const float2* __restrict__ stats,
    u16* __restrict__ xt) {
  __shared__ float T[64][65];
  int b = blockIdx.z;
  int s0 = blockIdx.x * 64, c0 = blockIdx.y * 64;
  int t = threadIdx.x;
  {
    int tx = t & 15, ty = t >> 4;
    const float* xb = x + ((size_t)b * Cch + c0) * Ssp + s0;
#pragma unroll
    for (int i = 0; i < 4; ++i) {
      int c = ty + 16 * i;
      float2 af = stats[(size_t)b * Cch + c0 + c];
      float4 v = *(const float4*)&xb[(size_t)c * Ssp + tx * 4];
      T[c][tx * 4 + 0] = v.x * af.x + af.y;
      T[c][tx * 4 + 1] = v.y * af.x + af.y;
      T[c][tx * 4 + 2] = v.z * af.x + af.y;
      T[c][tx * 4 + 3] = v.w * af.x + af.y;
    }
  }
  __syncthreads();
  {
    int cx = t & 7, sy = t >> 3;
    u16* ob = xt + ((size_t)b * Ssp + s0) * Cch + c0;
#pragma unroll
    for (int i = 0; i < 2; ++i) {
      int s = sy + 32 * i;
      union { u16 h[8]; uint4 v4; } pk;
#pragma unroll
      for (int j = 0; j < 8; ++j) pk.h[j] = f2bf(T[cx * 8 + j][s]);
      *(uint4*)&ob[(size_t)s * Cch + cx * 8] = pk.v4;
    }
  }
}

// ---------------- W[c][d] fp32 (512x512) -> Wt[d][c] bf16, 4 weights ----------
__global__ __launch_bounds__(256) void wxpose(
    const float* __restrict__ w0, const float* __restrict__ w1,
    const float* __restrict__ w2, const float* __restrict__ w3,
    u16* __restrict__ dst) {
  const float* W = blockIdx.z == 0 ? w0 : blockIdx.z == 1 ? w1
                   : blockIdx.z == 2 ? w2 : w3;
  u16* D = dst + (size_t)blockIdx.z * Cch * Cch;
  __shared__ float T[64][65];
  int d0 = blockIdx.x * 64, c0 = blockIdx.y * 64;
  int t = threadIdx.x;
  {
    int tx = t & 15, ty = t >> 4;
#pragma unroll
    for (int i = 0; i < 4; ++i) {
      int c = ty + 16 * i;
      float4 v = *(const float4*)&W[(size_t)(c0 + c) * Cch + d0 + tx * 4];
      T[c][tx * 4 + 0] = v.x; T[c][tx * 4 + 1] = v.y;
      T[c][tx * 4 + 2] = v.z; T[c][tx * 4 + 3] = v.w;
    }
  }
  __syncthreads();
  {
    int cx = t & 7, dy = t >> 3;
#pragma unroll
    for (int i = 0; i < 2; ++i) {
      int d = dy + 32 * i;
      union { u16 h[8]; uint4 v4; } pk;
#pragma unroll
      for (int j = 0; j < 8; ++j) pk.h[j] = f2bf(T[cx * 8 + j][d]);
      *(uint4*)&D[(size_t)(d0 + d) * Cch + c0 + cx * 8] = pk.v4;
    }
  }
}

// ---- R12: 256x256 BK=64 8-wave NT GEMM, 2 barriers/tile, counted lgkm -------
// 8 waves 2(M)x4(N); per-wave 128x64 = 8 m-frags x 4 n-frags (32 f32x4 acc).
// LDS per operand: 2 bufs x 32KB; buf = [khalf][16 segs][16rows x 32k unit],
// unit = proven row-pair-XOR layout (pair-line q=r>>1; logical chunk
// c=(r&1)*4+k/8; phys p = c^(q&7); 2-way max bank aliasing = free).
// Per tile: two khalf superphases. Each: {vm-wait(counted) -> BAR ->
// issue 12 ds_reads (B x4, A m0-3, A m4-7) -> lgkm(4): first 8 done ->
// MFMA m0-3 (16) WHILE A m4-7's reads drain -> STG next-tile khalf (4 vmem)
// -> lgkm(0) -> MFMA m4-7 (16)}. vm counting: tile-start vm(4) drains kh0
// (issued a full tile ago); kh1-point vm(4) drains kh1 (kh0(t+1) in flight).
// EPI 0: bf16 + bias(n<512?bias:b2)  EPI 1: bf16 + bias[m]  EPI 2: bf16 *scale
// EPI 3: bf16                        EPI 4: f32 + bias[m] + resid
template <int EPI>
__global__ __launch_bounds__(512, 2) void mfma_ntf(
    const u16* __restrict__ A, size_t sAb, int lda,
    const u16* __restrict__ B, size_t sBb, int ldb,
    void* __restrict__ Out, size_t sOb, int ldo,
    const float* __restrict__ bias,
    const float* __restrict__ bias2_or_resid, size_t sRb, int K) {
  __shared__ u16 As[2 * 16384];  // 64 KB
  __shared__ u16 Bs[2 * 16384];  // 64 KB

  // bijective XCD-aware swizzle (R7)
  const int nx = gridDim.x, ny = gridDim.y;
  const int pb = nx * ny;
  const int nwg = pb * gridDim.z;
  const int flat = (blockIdx.z * ny + blockIdx.y) * nx + blockIdx.x;
  const int qq = nwg >> 3, rr = nwg & 7;
  const int xcd = flat & 7, lid = flat >> 3;
  const int nf2 = (xcd < rr ? xcd * (qq + 1) : rr * (qq + 1) + (xcd - rr) * qq) + lid;
  const int b = nf2 / pb;
  const int rem = nf2 - b * pb;
  const int m0 = (rem / nx) * 256, n0 = (rem % nx) * 256;

  const int tid = threadIdx.x;
  const int lane = tid & 63, wave = tid >> 6;  // 0..7
  const int wm = wave >> 2, wn = wave & 3;     // 2(M) x 4(N)
  const int quad = lane >> 4, l16 = lane & 15;

  // staging decode (proven): phys chunk p = lane&7 of pair q' = lane>>3 within
  // a 16-row unit; logical c = p ^ q' -> row 2q' + (c>>2), k-off (c&3)*8.
  const int sp = lane & 7, sq = lane >> 3;
  const int scl = sp ^ sq;
  const int srow = 2 * sq + (scl >> 2);
  const int scol = (scl & 3) * 8;

  // fragment-read per-lane offset within a 512-elem unit
  const int vbase =
      ((l16 >> 1) << 6) + ((((l16 & 1) << 2) | quad) ^ (l16 >> 1)) * 8;

  const u16* Ab = A + (size_t)b * sAb + (size_t)m0 * lda;
  const u16* Bb = B + (size_t)b * sBb + (size_t)n0 * ldb;

  f32x4 acc[8][4] = {};

  // stage both segment-groups (su=wave, su=8+wave) of khalf kh for tile kt1
  // into buffer nbuf: 4 gload_lds per wave (A,B x 2 segs), issued as one group.
#define STGH(kh, kt1, nbuf)                                                    \
  {                                                                            \
    _Pragma("unroll") for (int i_ = 0; i_ < 2; ++i_) {                         \
      const int su_ = i_ * 8 + wave;                                           \
      gload_lds16(Ab + (size_t)(su_ * 16 + srow) * lda + (kt1) * 64 +          \
                      (kh) * 32 + scol,                                        \
                  As + (nbuf) * 16384 + (kh) * 8192 + su_ * 512);              \
      gload_lds16(Bb + (size_t)(su_ * 16 + srow) * ldb + (kt1) * 64 +          \
                      (kh) * 32 + scol,                                        \
                  Bs + (nbuf) * 16384 + (kh) * 8192 + su_ * 512);              \
    }                                                                          \
  }

  // fragment loads from buf cur
#define LDA(mf, kk) \
  (*(const bf16x8*)&As[cur * 16384 + (kk) * 8192 + (wm * 8 + (mf)) * 512 + vbase])
#define LDB(nf, kk) \
  (*(const bf16x8*)&Bs[cur * 16384 + (kk) * 8192 + (wn * 4 + (nf)) * 512 + vbase])

#define BAR asm volatile("s_barrier" ::: "memory")
#define WAIT_VM(n) asm volatile("s_waitcnt vmcnt(" #n ")" ::: "memory")
#define WAIT_LGKM(n)                                      \
  asm volatile("s_waitcnt lgkmcnt(" #n ")" ::: "memory"); \
  __builtin_amdgcn_sched_barrier(0)
#define SB0 __builtin_amdgcn_sched_barrier(0)

  // prologue: stage tile 0 into buf 0, kh0 group first (vm-count ordering)
  STGH(0, 0, 0)
  STGH(1, 0, 0)

  const int nk = K >> 6;
  bf16x8 bf[4], a[4], a2[4];
  for (int kt = 0; kt < nk; ++kt) {
    const int cur = kt & 1;
    const int nbuf = cur ^ 1;
    const bool nxt = (kt + 1 < nk);

    // ================= khalf 0 =================
    WAIT_VM(4);  // drain kh0(t) (oldest 4); kh1(t) stays in flight
    BAR;         // all waves' kh0 loads landed -> buf[cur].kh0 valid
#pragma unroll
    for (int i = 0; i < 4; ++i) bf[i] = LDB(i, 0);
#pragma unroll
    for (int i = 0; i < 4; ++i) a[i] = LDA(i, 0);
    SB0;  // pin group order: these 8 are the oldest lgkm ops
#pragma unroll
    for (int i = 0; i < 4; ++i) a2[i] = LDA(4 + i, 0);
    WAIT_LGKM(4);  // first 8 (bf, a) done; a2's 4 drain under MFMA below
    __builtin_amdgcn_s_setprio(1);
#pragma unroll
    for (int mf = 0; mf < 4; ++mf)
#pragma unroll
      for (int nf = 0; nf < 4; ++nf)
        acc[mf][nf] = __builtin_amdgcn_mfma_f32_16x16x32_bf16(
            a[mf], bf[nf], acc[mf][nf], 0, 0, 0);
    __builtin_amdgcn_s_setprio(0);
    if (nxt) STGH(0, kt + 1, nbuf)  // 4 vmem: kh0 of t+1
    WAIT_LGKM(0);                   // a2 ready
    __builtin_amdgcn_s_setprio(1);
#pragma unroll
    for (int mf = 0; mf < 4; ++mf)
#pragma unroll
      for (int nf = 0; nf < 4; ++nf)
        acc[4 + mf][nf] = __builtin_amdgcn_mfma_f32_16x16x32_bf16(
            a2[mf], bf[nf], acc[4 + mf][nf], 0, 0, 0);
    __builtin_amdgcn_s_setprio(0);

    // ================= khalf 1 =================
    if (nxt) { WAIT_VM(4); } else { WAIT_VM(0); }  // drain kh1(t)
    BAR;  // all waves' kh1 loads landed -> buf[cur].kh1 valid
#pragma unroll
    for (int i = 0; i < 4; ++i) bf[i] = LDB(i, 1);
#pragma unroll
    for (int i = 0; i < 4; ++i) a[i] = LDA(i, 1);
    SB0;
#pragma unroll
    for (int i = 0; i < 4; ++i) a2[i] = LDA(4 + i, 1);
    WAIT_LGKM(4);
    __builtin_amdgcn_s_setprio(1);
#pragma unroll
    for (int mf = 0; mf < 4; ++mf)
#pragma unroll
      for (int nf = 0; nf < 4; ++nf)
        acc[mf][nf] = __builtin_amdgcn_mfma_f32_16x16x32_bf16(
            a[mf], bf[nf], acc[mf][nf], 0, 0, 0);
    __builtin_amdgcn_s_setprio(0);
    if (nxt) STGH(1, kt + 1, nbuf)  // 4 vmem: kh1 of t+1
    WAIT_LGKM(0);
    __builtin_amdgcn_s_setprio(1);
#pragma unroll
    for (int mf = 0; mf < 4; ++mf)
#pragma unroll
      for (int nf = 0; nf < 4; ++nf)
        acc[4 + mf][nf] = __builtin_amdgcn_mfma_f32_16x16x32_bf16(
            a2[mf], bf[nf], acc[4 + mf][nf], 0, 0, 0);
    __builtin_amdgcn_s_setprio(0);
  }
#undef STGH
#undef LDA
#undef LDB

  const float SCALE = 0.044194173824159216f;  // 512^-0.5
#pragma unroll
  for (int mf = 0; mf < 8; ++mf) {
#pragma unroll
    for (int nf = 0; nf < 4; ++nf) {
      int n = n0 + wn * 64 + nf * 16 + l16;
      float bn = 0.f;
      if constexpr (EPI == 0)
        bn = (n < 512) ? bias[n] : bias2_or_resid[n - 512];
#pragma unroll
      for (int reg = 0; reg < 4; ++reg) {
        int m = m0 + wm * 128 + mf * 16 + quad * 4 + reg;
        float v = acc[mf][nf][reg];
        size_t idx = (size_t)b * sOb + (size_t)m * ldo + n;
        if constexpr (EPI == 0) {
          ((u16*)Out)[idx] = f2bf(v + bn);
        } else if constexpr (EPI == 1) {
          ((u16*)Out)[idx] = f2bf(v + bias[m]);
        } else if constexpr (EPI == 2) {
          ((u16*)Out)[idx] = f2bf(v * SCALE);
        } else if constexpr (EPI == 3) {
          ((u16*)Out)[idx] = f2bf(v);
        } else {
          ((float*)Out)[idx] =
              v + bias[m] + bias2_or_resid[(size_t)b * sRb + (size_t)m * ldo + n];
        }
      }
    }
  }
}

// ---------------- Softmax over bf16 rows of Sc [nb*S][S], in place ------------
__global__ __launch_bounds__(256) void softmax_kernel(u16* __restrict__ Sc) {
  size_t row = blockIdx.x;
  u16* rp = Sc + row * (size_t)Ssp;
  uint2 u = ((const uint2*)rp)[threadIdx.x];  // 4 bf16
  const u16* ph = (const u16*)&u;
  float v0 = bf2f(ph[0]), v1 = bf2f(ph[1]), v2 = bf2f(ph[2]), v3 = bf2f(ph[3]);
  float mx = fmaxf(fmaxf(v0, v1), fmaxf(v2, v3));
#pragma unroll
  for (int off = 32; off > 0; off >>= 1) mx = fmaxf(mx, __shfl_xor(mx, off));
  __shared__ float sm[4];
  __shared__ float sd[4];
  int wid = threadIdx.x >> 6;
  if ((threadIdx.x & 63) == 0) sm[wid] = mx;
  __syncthreads();  // also: all row reads complete before any write below
  mx = fmaxf(fmaxf(sm[0], sm[1]), fmaxf(sm[2], sm[3]));
  float e0 = __expf(v0 - mx), e1 = __expf(v1 - mx);
  float e2 = __expf(v2 - mx), e3 = __expf(v3 - mx);
  float s = e0 + e1 + e2 + e3;
#pragma unroll
  for (int off = 32; off > 0; off >>= 1) s += __shfl_xor(s, off);
  if ((threadIdx.x & 63) == 0) sd[wid] = s;
  __syncthreads();
  s = sd[0] + sd[1] + sd[2] + sd[3];
  float inv = 1.f / s;
  union { u16 s4[4]; uint2 v2; } pk;
  pk.s4[0] = f2bf(e0 * inv); pk.s4[1] = f2bf(e1 * inv);
  pk.s4[2] = f2bf(e2 * inv); pk.s4[3] = f2bf(e3 * inv);
  ((uint2*)rp)[threadIdx.x] = pk.v2;
}

extern "C" void kernel_launch(void* const* d_in, const int* in_sizes, int n_in,
                              void* d_out, int out_size, void* d_ws, size_t ws_size,
                              hipStream_t stream) {
  (void)in_sizes; (void)n_in; (void)out_size;
  const float* x   = (const float*)d_in[0];
  const float* gns = (const float*)d_in[1];
  const float* gnb = (const float*)d_in[2];
  const float* Wq  = (const float*)d_in[3];
  const float* bq  = (const float*)d_in[4];
  const float* Wk  = (const float*)d_in[5];
  const float* bk  = (const float*)d_in[6];
  const float* Wv  = (const float*)d_in[7];
  const float* bv  = (const float*)d_in[8];
  const float* Wt  = (const float*)d_in[9];
  const float* bt  = (const float*)d_in[10];
  float* out = (float*)d_out;
  char* ws = (char*)d_ws;

  // Workspace:
  //   qkt @ 0MB   (64MB bf16 [b][s][1024], q|k fused) -> o_t aliases its start
  //   v   @ 64MB  (32MB bf16 [b][d][s])
  //   W_t @ 96MB  (4 x 0.5MB bf16 [d][c]: q,k,v,t -> Wq|Wk contiguous = fused N)
  //   stats @98MB (256KB float2)
  //   xt  @ 99MB  (32MB bf16 [b][s][c]) -> dead after projections
  //   Sc  @ 99MB  (NB*2MB bf16, overlays xt; softmax in place)
  const size_t QKSZ = (size_t)Bsz * Ssp * 1024 * 2;  // 64 MB
  u16* qkt = (u16*)ws;
  u16* vv  = (u16*)(ws + QKSZ);
  u16* Wts = (u16*)(ws + (96ull << 20));
  float2* stats = (float2*)(ws + (98ull << 20));
  u16* xt  = (u16*)(ws + (99ull << 20));
  u16* Sc  = xt;
  u16* ot  = qkt;

  int NB;  // batches per score chunk (Sc = NB*2MB @ 99MB); ws_size is constant
  if (ws_size >= (163ull << 20)) NB = 32;
  else if (ws_size >= (131ull << 20)) NB = 16;
  else NB = 8;

  const size_t WSZ = (size_t)Cch * Cch;
  u16* Wvt = Wts + 2 * WSZ;
  u16* Wtt = Wts + 3 * WSZ;

  const size_t sSC  = (size_t)Ssp * Cch;   // xt / o_t per-batch elems
  const size_t sQK  = (size_t)Ssp * 1024;  // qkt per-batch elems
  const size_t sCS  = (size_t)Cch * Ssp;   // v / x / out per-batch elems
  const size_t sScB = (size_t)Ssp * Ssp;   // score per-batch elems (bf16)
  dim3 blk(256);
  dim3 blk8(512);

  gnstats_kernel<<<dim3(Bsz * Grp), blk, 0, stream>>>(x, gns, gnb, stats);
  xpose_gn<<<dim3(Ssp / 64, Cch / 64, Bsz), blk, 0, stream>>>(x, stats, xt);
  wxpose<<<dim3(8, 8, 4), blk, 0, stream>>>(Wq, Wk, Wv, Wt, Wts);

  // Grids: x = N/256, y = M/256, z = batch
  // fused q|k: m=s(1024), n=dq|dk(1024), k=c(512): A=xt, B=Wq_t|Wk_t
  mfma_ntf<0><<<dim3(4, 4, Bsz), blk8, 0, stream>>>(
      xt, sSC, Cch, Wts, 0, Cch, qkt, sQK, 1024, bq, bk, 0, Cch);
  // v: m=d(512), n=s(1024), k=c(512): A=Wv_t, B=xt -> v[d][s] + bias[m]
  mfma_ntf<1><<<dim3(4, 2, Bsz), blk8, 0, stream>>>(
      Wvt, 0, Cch, xt, sSC, Cch, vv, sCS, Ssp, bv, nullptr, 0, Cch);

  for (int b0 = 0; b0 < Bsz; b0 += NB) {
    int nb = (b0 + NB <= Bsz) ? NB : (Bsz - b0);
    // scores: m=s, n=s', k=d: A=q (qkt+0), B=k (qkt+512) -> Sc bf16 * C^-0.5
    mfma_ntf<2><<<dim3(4, 4, nb), blk8, 0, stream>>>(
        qkt + b0 * sQK, sQK, 1024, qkt + b0 * sQK + 512, sQK, 1024,
        Sc, sScB, Ssp, nullptr, nullptr, 0, Cch);
    softmax_kernel<<<dim3(nb * Ssp), blk, 0, stream>>>(Sc);
    // PV: m=s(1024), n=c(512), k=t(1024): A=P bf16, B=v -> o_t[s][c]
    mfma_ntf<3><<<dim3(2, 4, nb), blk8, 0, stream>>>(
        Sc, sScB, Ssp, vv + b0 * sCS, sCS, Ssp,
        ot + b0 * sSC, sSC, Cch, nullptr, nullptr, 0, Ssp);
  }

  // final: m=d(512), n=s(1024), k=c(512): A=Wt_t, B=o_t -> fp32 +bias[m]+x
  mfma_ntf<4><<<dim3(4, 2, Bsz), blk8, 0, stream>>>(
      Wtt, 0, Cch, ot, sSC, Cch, out, sCS, Ssp, bt, x, sCS, Cch);
}